// Round 1
// baseline (118.396 us; speedup 1.0000x reference)
//
#include <hip/hip_runtime.h>

#define NQ  4
#define DIM 16
#define NL  3
#define HD  128

__global__ __launch_bounds__(256) void rqa_kernel(
    const float* __restrict__ edge,   // (N,128)
    const float* __restrict__ W,      // (4,128)
    const float* __restrict__ b,      // (4,)
    const float* __restrict__ qw,     // (3,4,3) phi,theta,omega
    float* __restrict__ out, int N)
{
    __shared__ float rotm[NL * NQ][4];   // a_re, a_im, b_re, b_im per Rot gate

    const int tid = threadIdx.x;
    if (tid < NL * NQ) {
        float phi = qw[tid * 3 + 0];
        float th  = qw[tid * 3 + 1];
        float om  = qw[tid * 3 + 2];
        float ct, st, ca, sa, cb, sb;
        sincosf(0.5f * th, &st, &ct);
        sincosf(0.5f * (phi + om), &sa, &ca);
        sincosf(0.5f * (phi - om), &sb, &cb);
        // U00 = e^{-i(phi+om)/2} c ; U01 = -e^{i(phi-om)/2} s
        // U10 = -conj(U01) ; U11 = conj(U00)
        rotm[tid][0] =  ca * ct;
        rotm[tid][1] = -sa * ct;
        rotm[tid][2] = -cb * st;
        rotm[tid][3] = -sb * st;
    }
    __syncthreads();

    const int gid = blockIdx.x * 256 + tid;
    if (gid >= N) return;

    // ---------- projection: acc[o] = edge[gid,:] . W[o,:] + b[o] ----------
    const float4* __restrict__ row = (const float4*)(edge + (size_t)gid * HD);
    float acc[NQ];
    #pragma unroll
    for (int o = 0; o < NQ; ++o) acc[o] = b[o];
    #pragma unroll 8
    for (int i = 0; i < HD / 4; ++i) {
        float4 x = row[i];
        #pragma unroll
        for (int o = 0; o < NQ; ++o) {
            acc[o] += x.x * W[o * HD + 4 * i + 0]
                    + x.y * W[o * HD + 4 * i + 1]
                    + x.z * W[o * HD + 4 * i + 2]
                    + x.w * W[o * HD + 4 * i + 3];
        }
    }

    // angles (same every layer: data re-uploading) -> cos/sin of a/2
    const float PIF = 3.14159265358979323846f;
    float cy[NQ], sy[NQ];
    #pragma unroll
    for (int w = 0; w < NQ; ++w) {
        float a = PIF * tanhf(acc[w]);
        sincosf(0.5f * a, &sy[w], &cy[w]);
    }

    // ---------- statevector in registers (wire w <-> bit 3-w, wire0 = MSB) ----------
    float sr[DIM], si[DIM];
    #pragma unroll
    for (int n = 0; n < DIM; ++n) { sr[n] = 0.f; si[n] = 0.f; }
    sr[0] = 1.f;

    for (int l = 0; l < NL; ++l) {
        // RY embedding (real rotation) on wires 0..3
        #pragma unroll
        for (int w = 0; w < NQ; ++w) {
            const int str = 1 << (3 - w);
            const float c = cy[w], s = sy[w];
            #pragma unroll
            for (int i0 = 0; i0 < DIM; ++i0) {
                if (i0 & str) continue;
                const int i1 = i0 | str;
                float r0 = c * sr[i0] - s * sr[i1];
                float m0 = c * si[i0] - s * si[i1];
                float r1 = s * sr[i0] + c * sr[i1];
                float m1 = s * si[i0] + c * si[i1];
                sr[i0] = r0; si[i0] = m0; sr[i1] = r1; si[i1] = m1;
            }
        }
        // Rot gates (constant, from LDS broadcast)
        #pragma unroll
        for (int w = 0; w < NQ; ++w) {
            const float ar = rotm[l * NQ + w][0];
            const float ai = rotm[l * NQ + w][1];
            const float br = rotm[l * NQ + w][2];
            const float bi = rotm[l * NQ + w][3];
            const int str = 1 << (3 - w);
            #pragma unroll
            for (int i0 = 0; i0 < DIM; ++i0) {
                if (i0 & str) continue;
                const int i1 = i0 | str;
                const float s0r = sr[i0], s0i = si[i0];
                const float s1r = sr[i1], s1i = si[i1];
                sr[i0] =  ar * s0r - ai * s0i + br * s1r - bi * s1i;
                si[i0] =  ar * s0i + ai * s0r + br * s1i + bi * s1r;
                sr[i1] = -br * s0r - bi * s0i + ar * s1r + ai * s1i;
                si[i1] = -br * s0i + bi * s0r + ar * s1i - ai * s1r;
            }
        }
        // CNOT ring (0,1),(1,2),(2,3),(3,0): register swaps
        #pragma unroll
        for (int w = 0; w < NQ; ++w) {
            const int cb_ = 1 << (3 - w);
            const int tb_ = 1 << (3 - ((w + 1) & 3));
            #pragma unroll
            for (int n = 0; n < DIM; ++n) {
                if ((n & cb_) && !(n & tb_)) {
                    const int m = n | tb_;
                    float t0 = sr[n]; sr[n] = sr[m]; sr[m] = t0;
                    float t1 = si[n]; si[n] = si[m]; si[m] = t1;
                }
            }
        }
    }

    // <Z_0> = sum_{bit3=0} |amp|^2 - sum_{bit3=1} |amp|^2, then sigmoid
    float z = 0.f;
    #pragma unroll
    for (int n = 0; n < DIM; ++n) {
        const float p = sr[n] * sr[n] + si[n] * si[n];
        z = (n < 8) ? (z + p) : (z - p);
    }
    out[gid] = 1.0f / (1.0f + expf(-z));
}

extern "C" void kernel_launch(void* const* d_in, const int* in_sizes, int n_in,
                              void* d_out, int out_size, void* d_ws, size_t ws_size,
                              hipStream_t stream) {
    const float* edge = (const float*)d_in[0];
    const float* W    = (const float*)d_in[1];
    const float* b    = (const float*)d_in[2];
    const float* qw   = (const float*)d_in[3];
    float* out = (float*)d_out;

    const int N = in_sizes[0] / HD;
    const int blocks = (N + 255) / 256;
    rqa_kernel<<<dim3(blocks), dim3(256), 0, stream>>>(edge, W, b, qw, out, N);
}